// Round 15
// baseline (193.369 us; speedup 1.0000x reference)
//
#include <hip/hip_runtime.h>
#include <cstddef>
#include <cstdint>

#define BB 4
#define NN 6144
#define DD 64
#define HID 512
#define OUTD 64
#define CAP 512
#define RSPLIT 2

typedef unsigned long long ull;
typedef unsigned int u32;
typedef unsigned short u16;
typedef unsigned char u8;
typedef __attribute__((ext_vector_type(8))) short short8_t;
typedef __attribute__((ext_vector_type(4))) float floatx4;

// ---- ws layout (byte offsets) ----
#define OFF_ROWFIN 0
#define OFF_COLFIN 196608
#define OFF_WT     393216
#define OFF_F1T    2162688
#define OFF_F2T    5308416
#define OFF_RBM    8454144
#define OFF_CBM    10813440
#define OFF_CNTR   13172736
#define OFF_CNTC   13173504
#define OFF_LISTR  13174272
#define OFF_LISTC  13567488

#define WT1_OFF 0
#define WT2_OFF 65536
#define WT3_OFF 327680
#define WT4_OFF 589824
#define WT5_OFF 851968
#define WT_TOTAL 884736

__device__ __forceinline__ unsigned int fkey(float v) {
    unsigned int u = __float_as_uint(v);
    return (u & 0x80000000u) ? ~u : (u | 0x80000000u);
}

__device__ __forceinline__ float inv16(u32 k16) {
    u32 u = k16 << 16;
    return (u & 0x80000000u) ? __uint_as_float(u & 0x7fffffffu)
                             : __uint_as_float(~u);
}

__device__ __forceinline__ u16 f2bf(float f) {
    unsigned int u = __float_as_uint(f);
    u += 0x7FFFu + ((u >> 16) & 1u);
    return (u16)(u >> 16);
}

// two floats -> two fp8 (chip-native fp8; self-consistent with fp8 MFMA)
__device__ __forceinline__ u32 f2fp8x2(float a, float b) {
    return (u32)__builtin_amdgcn_cvt_pk_fp8_f32(a, b, 0, false) & 0xffffu;
}

// ---- prep: ws init + weights->fp8 tiled + feats->bf16 tiled ----
__global__ __launch_bounds__(256) void prep_kernel(
    const float* __restrict__ w1, const float* __restrict__ w2,
    const float* __restrict__ w3, const float* __restrict__ w4,
    const float* __restrict__ w5,
    const float* __restrict__ f1, const float* __restrict__ f2,
    u8* __restrict__ wt8, u16* __restrict__ f1t, u16* __restrict__ f2t,
    ull* __restrict__ finals, int* __restrict__ cnts)
{
    int idx = blockIdx.x * 256 + threadIdx.x;

    if (idx < 2 * BB * NN) finals[idx] = 0ULL;
    if (idx < 384) cnts[idx] = 0;

    if (idx < WT_TOTAL) {
        const float* w; u8* o; int K, nsh, li;
        if (idx < 65536)        { w = w1; o = wt8 + WT1_OFF; K = 128; nsh = 9; li = idx; }
        else if (idx < 327680)  { w = w2; o = wt8 + WT2_OFF; K = 512; nsh = 9; li = idx - 65536; }
        else if (idx < 589824)  { w = w3; o = wt8 + WT3_OFF; K = 512; nsh = 9; li = idx - 327680; }
        else if (idx < 851968)  { w = w4; o = wt8 + WT4_OFF; K = 512; nsh = 9; li = idx - 589824; }
        else                    { w = w5; o = wt8 + WT5_OFF; K = 512; nsh = 6; li = idx - 851968; }
        int k = li >> nsh;
        int n = li & ((1 << nsh) - 1);
        u8 v = (u8)(f2fp8x2(w[li], 0.0f) & 0xff);
        int lane = (n & 15) | (((k >> 3) & 3) << 4);
        o[(((size_t)(n >> 4) * (K >> 5) + (k >> 5)) * 64 + lane) * 8 + (k & 7)] = v;
    }

    {
        const int TE = BB * NN * DD;
        const float* src; u16* dst; int e;
        if (idx < TE) { src = f1; dst = f1t; e = idx; }
        else          { src = f2; dst = f2t; e = idx - TE; }
        int k  = e & 63;
        int rn = e >> 6;
        int b  = rn / NN;
        int r  = rn - b * NN;
        int R  = r >> 7, rb = (r >> 4) & 7;
        int kb = k >> 5, lane = (r & 15) | (((k >> 3) & 3) << 4), j = k & 7;
        dst[(size_t)(b * 48 + R) * 8192 + ((rb * 2 + kb) * 64 + lane) * 8 + j] = f2bf(src[e]);
    }
}

// ---- Kernel A: bf16 MFMA sim, 128x128 tile, 4 waves x (32 rows x 128 cols),
//      wave-local row-max, LDS col-merge; TRANSPOSED maxima [b][C][n] ----
__global__ __launch_bounds__(256, 4) void simb_kernel(
    const u16* __restrict__ f1t, const u16* __restrict__ f2t,
    u16* __restrict__ rbm, u16* __restrict__ cbm)
{
    __shared__ __align__(16) u16 sA[8192];
    __shared__ __align__(16) u16 sB[8192];
    __shared__ float cv[4][128];
    const int R = blockIdx.x, C = blockIdx.y, b = blockIdx.z;
    const int t = threadIdx.x, lane = t & 63, w = t >> 6;
    const int l15 = lane & 15, l4 = lane >> 4;

    const u16* Ag = f1t + (size_t)(b * 48 + R) * 8192;
    const u16* Bg = f2t + (size_t)(b * 48 + C) * 8192;

    #pragma unroll
    for (int rnd = 0; rnd < 4; ++rnd) {
        int c = rnd * 256 + t;
        *reinterpret_cast<uint4*>(&sA[c * 8]) = *reinterpret_cast<const uint4*>(Ag + c * 8);
        *reinterpret_cast<uint4*>(&sB[c * 8]) = *reinterpret_cast<const uint4*>(Bg + c * 8);
    }
    __syncthreads();

    floatx4 acc[2][8];
    #pragma unroll
    for (int i = 0; i < 2; ++i)
        #pragma unroll
        for (int j = 0; j < 8; ++j) acc[i][j] = (floatx4)(0.0f);

    #pragma unroll
    for (int kb = 0; kb < 2; ++kb) {
        short8_t afr[2];
        #pragma unroll
        for (int i = 0; i < 2; ++i)
            afr[i] = *reinterpret_cast<const short8_t*>(
                &sA[(((2 * w + i) * 2 + kb) * 64 + lane) * 8]);
        #pragma unroll
        for (int j = 0; j < 8; ++j) {
            short8_t bfr = *reinterpret_cast<const short8_t*>(
                &sB[((j * 2 + kb) * 64 + lane) * 8]);
            #pragma unroll
            for (int i = 0; i < 2; ++i)
                acc[i][j] = __builtin_amdgcn_mfma_f32_16x16x32_bf16(
                    afr[i], bfr, acc[i][j], 0, 0, 0);
        }
    }

    // row-max: fully wave-local (all 128 cols in-wave); 4-shfl over l15
    #pragma unroll
    for (int i = 0; i < 2; ++i) {
        #pragma unroll
        for (int reg = 0; reg < 4; ++reg) {
            float v = acc[i][0][reg];
            #pragma unroll
            for (int j = 1; j < 8; ++j) v = fmaxf(v, acc[i][j][reg]);
            v = fmaxf(v, __shfl_xor(v, 1));
            v = fmaxf(v, __shfl_xor(v, 2));
            v = fmaxf(v, __shfl_xor(v, 4));
            v = fmaxf(v, __shfl_xor(v, 8));
            if (l15 == 0) {
                int row = R * 128 + w * 32 + i * 16 + l4 * 4 + reg;
                rbm[((size_t)b * 48 + C) * NN + row] = (u16)(fkey(v) >> 16);
            }
        }
    }

    // col-max: in-lane over (i,reg), 2-shfl over l4, then 4-wave LDS merge
    #pragma unroll
    for (int j = 0; j < 8; ++j) {
        float v = acc[0][j][0];
        #pragma unroll
        for (int i = 0; i < 2; ++i)
            #pragma unroll
            for (int reg = 0; reg < 4; ++reg) v = fmaxf(v, acc[i][j][reg]);
        v = fmaxf(v, __shfl_xor(v, 16));
        v = fmaxf(v, __shfl_xor(v, 32));
        if (l4 == 0) cv[w][j * 16 + l15] = v;
    }
    __syncthreads();
    if (t < 128) {
        float v = fmaxf(fmaxf(cv[0][t], cv[1][t]), fmaxf(cv[2][t], cv[3][t]));
        cbm[((size_t)b * 48 + R) * NN + C * 128 + t] = (u16)(fkey(v) >> 16);
    }
}

// ---- scan (merged row/col via blockIdx.y): transposed bm reads,
//      block-aggregated candidate append ----
__global__ __launch_bounds__(256) void scan_kernel(
    const u16* __restrict__ rbm, const u16* __restrict__ cbm,
    int* __restrict__ cntR, int* __restrict__ cntC,
    int* __restrict__ listR, int* __restrict__ listC)
{
    const u16* bm = blockIdx.y ? cbm : rbm;
    int* cnt  = blockIdx.y ? cntC : cntR;
    int* list = blockIdx.y ? listC : listR;

    __shared__ int lcnt[48];
    __shared__ int lbase[48];
    const int t = threadIdx.x;
    if (t < 48) lcnt[t] = 0;
    const int idx = blockIdx.x * 256 + t;
    const int b = (blockIdx.x * 256) / NN;
    const int n = idx - b * NN;

    u16 ks[48];
    #pragma unroll
    for (int c = 0; c < 48; ++c)
        ks[c] = bm[((size_t)b * 48 + c) * NN + n];

    u16 mx = 0;
    #pragma unroll
    for (int c = 0; c < 48; ++c) mx = ks[c] > mx ? ks[c] : mx;
    // margin: worst-case bf16 sim error |S~-S| <= 2^-8 * sum|a_k b_k| <= 0.0039
    // (round-to-nearest f2bf, unit vectors); listing the true block needs
    // margin >= 2*0.0039 = 0.0078; 0.010 gives 28% cushion.
    float thr = inv16(mx) - 0.010f;
    u32 m0 = 0, m1 = 0;
    #pragma unroll
    for (int c = 0; c < 48; ++c) {
        if (inv16((u32)ks[c] + 1) >= thr) {
            if (c < 32) m0 |= 1u << c; else m1 |= 1u << (c - 32);
        }
    }
    __syncthreads();
    {
        u32 a = m0;
        while (a) { int c = __builtin_ctz(a); a &= a - 1; atomicAdd(&lcnt[c], 1); }
        a = m1;
        while (a) { int c = 32 + __builtin_ctz(a); a &= a - 1; atomicAdd(&lcnt[c], 1); }
    }
    __syncthreads();
    if (t < 48) { lbase[t] = atomicAdd(&cnt[b * 48 + t], lcnt[t]); lcnt[t] = 0; }
    __syncthreads();
    {
        u32 a = m0;
        while (a) {
            int c = __builtin_ctz(a); a &= a - 1;
            int pos = lbase[c] + atomicAdd(&lcnt[c], 1);
            if (pos < CAP) list[(b * 48 + c) * CAP + pos] = n;
        }
        a = m1;
        while (a) {
            int c = 32 + __builtin_ctz(a); a &= a - 1;
            int pos = lbase[c] + atomicAdd(&lcnt[c], 1);
            if (pos < CAP) list[(b * 48 + c) * CAP + pos] = n;
        }
    }
}

// ---- exact fp32 refine v3: LDS queries only, targets direct from global
//      (L1/L2-hot), 4q x 4t register blocking, 32-query iters ----
__global__ __launch_bounds__(256, 2) void refine_kernel(
    const float* __restrict__ f1, const float* __restrict__ f2,
    const int* __restrict__ cntR, const int* __restrict__ cntC,
    const int* __restrict__ listR, const int* __restrict__ listC,
    ull* __restrict__ rowfin, ull* __restrict__ colfin)
{
    const float* qfeat = blockIdx.z ? f2 : f1;
    const float* tfeat = blockIdx.z ? f1 : f2;
    const int* cnt  = blockIdx.z ? cntC : cntR;
    const int* list = blockIdx.z ? listC : listR;
    ull* fin = blockIdx.z ? colfin : rowfin;

    const int b = blockIdx.x / 48;
    const int C = blockIdx.x - b * 48;
    const int sub = blockIdx.y;
    int n_items = cnt[b * 48 + C];
    if (n_items > CAP) n_items = CAP;
    int chunk = (n_items + RSPLIT - 1) / RSPLIT;
    int lo = sub * chunk;
    int hi = lo + chunk; if (hi > n_items) hi = n_items;
    if (lo >= hi) return;

    __shared__ float sq[32 * 64];   // 8 KB: 32 staged query rows
    const int t = threadIdx.x;
    const int tq = t & 31;          // 32 target groups x 4 targets
    const int qg = t >> 5;          // 8 query groups x 4 queries
    const float* tb = tfeat + ((size_t)b * NN + C * 128) * 64;
    const int* mylist = list + (b * 48 + C) * CAP;

    for (int base = lo; base < hi; base += 32) {
        __syncthreads();   // protect sq reuse from previous iteration
        #pragma unroll
        for (int s = 0; s < 2; ++s) {
            int fi = s * 256 + t;           // 512 float4 = 32 rows x 16
            int q = fi >> 4, c4 = fi & 15;
            int lq = base + q;
            int nn = (lq < hi) ? mylist[lq] : mylist[lo];
            *reinterpret_cast<float4*>(&sq[q * 64 + c4 * 4]) =
                *reinterpret_cast<const float4*>(
                    qfeat + ((size_t)b * NN + nn) * 64 + c4 * 4);
        }
        __syncthreads();

        float acc[4][4];   // [q][t]
        #pragma unroll
        for (int j = 0; j < 4; ++j)
            #pragma unroll
            for (int i = 0; i < 4; ++i) acc[j][i] = 0.0f;

        #pragma unroll 4
        for (int kq = 0; kq < 16; ++kq) {
            float4 qv[4];
            #pragma unroll
            for (int j = 0; j < 4; ++j)
                qv[j] = *reinterpret_cast<const float4*>(
                    &sq[(qg * 4 + j) * 64 + kq * 4]);
            float4 tv[4];
            #pragma unroll
            for (int i = 0; i < 4; ++i)
                tv[i] = *reinterpret_cast<const float4*>(
                    tb + (tq * 4 + i) * 64 + kq * 4);
            #pragma unroll
            for (int j = 0; j < 4; ++j)
                #pragma unroll
                for (int i = 0; i < 4; ++i) {
                    acc[j][i] = fmaf(qv[j].x, tv[i].x, acc[j][i]);
                    acc[j][i] = fmaf(qv[j].y, tv[i].y, acc[j][i]);
                    acc[j][i] = fmaf(qv[j].z, tv[i].z, acc[j][i]);
                    acc[j][i] = fmaf(qv[j].w, tv[i].w, acc[j][i]);
                }
        }

        // per query: best over my 4 targets, then 5-step shfl over tq lanes
        #pragma unroll
        for (int j = 0; j < 4; ++j) {
            int lq = base + qg * 4 + j;
            bool valid = lq < hi;
            float bv = acc[j][0]; int bt = tq * 4;
            #pragma unroll
            for (int i = 1; i < 4; ++i)
                if (acc[j][i] > bv) { bv = acc[j][i]; bt = tq * 4 + i; }
            ull pk = ((ull)fkey(bv) << 32) | (u32)(~(u32)(C * 128 + bt));
            ull qq;
            qq = __shfl_xor(pk, 1);  pk = pk > qq ? pk : qq;
            qq = __shfl_xor(pk, 2);  pk = pk > qq ? pk : qq;
            qq = __shfl_xor(pk, 4);  pk = pk > qq ? pk : qq;
            qq = __shfl_xor(pk, 8);  pk = pk > qq ? pk : qq;
            qq = __shfl_xor(pk, 16); pk = pk > qq ? pk : qq;
            if (tq == 0 && valid) {
                int n = mylist[lq];
                atomicMax(&fin[(size_t)b * NN + n], pk);
            }
        }
    }
}

// ---- Kernel B: fp8 MFMA MLP, 96 pts/block, grid=256 (1 block/CU),
//      512 thr / 8 waves, 64ch/wave, stagger + setprio + 3-buf prefetch ----

#define MLP_STEP(BUF, KB)                                                        \
    {                                                                            \
        const int kb2 = ((KB) + woff) & (NKB - 1);                               \
        __builtin_amdgcn_s_setprio(1);                                           \
        _Pragma("unroll")                                                        \
        for (int jb = 0; jb < 6; ++jb) {                                         \
            const int pt = jb * 16 + l15;                                        \
            const int sp = (kb2 * 4 + l4) ^ (pt & 7);                            \
            long bfr = *reinterpret_cast<const long*>(act + pt * 512 + sp * 8);  \
            _Pragma("unroll")                                                    \
            for (int ia = 0; ia < 4; ++ia)                                       \
                acc[ia][jb] = __builtin_amdgcn_mfma_f32_16x16x32_fp8_fp8(        \
                    BUF[ia], bfr, acc[ia][jb], 0, 0, 0);                         \
        }                                                                        \
        __builtin_amdgcn_s_setprio(0);                                           \
        if ((KB) + 3 < NKB) {                                                    \
            const int kbp = ((KB) + 3 + woff) & (NKB - 1);                       \
            _Pragma("unroll")                                                    \
            for (int ia = 0; ia < 4; ++ia)                                       \
                BUF[ia] = *reinterpret_cast<const long*>(                        \
                    wt8 + (((size_t)(chBlk0 + ia) * NKB + kbp) * 64 + lane) * 8);\
        }                                                                        \
    }

template<int K>
__device__ __forceinline__ void mlp_layer8(
    u8* act, const u8* __restrict__ wt8,
    const float* __restrict__ bias, int lane, int wid)
{
    constexpr int NKB = K / 32;
    floatx4 acc[4][6];
    #pragma unroll
    for (int ia = 0; ia < 4; ++ia)
        #pragma unroll
        for (int jb = 0; jb < 6; ++jb)
            acc[ia][jb] = (floatx4)(0.0f);

    const int l15 = lane & 15, l4 = lane >> 4;
    const int chBlk0 = wid * 4;               // (wid*64)/16
    const int woff = (wid * 2) & (NKB - 1);   // per-wave kb stagger

    long a0[4], a1[4], a2[4];
    #pragma unroll
    for (int ia = 0; ia < 4; ++ia)
        a0[ia] = *reinterpret_cast<const long*>(
            wt8 + (((size_t)(chBlk0 + ia) * NKB + ((0 + woff) & (NKB - 1))) * 64 + lane) * 8);
    #pragma unroll
    for (int ia = 0; ia < 4; ++ia)
        a1[ia] = *reinterpret_cast<const long*>(
            wt8 + (((size_t)(chBlk0 + ia) * NKB + ((1 + woff) & (NKB - 1))) * 64 + lane) * 8);
    #pragma unroll
    for (int ia = 0; ia < 4; ++ia)
        a2[ia] = *reinterpret_cast<const long*>(
            wt8 + (((size_t)(chBlk0 + ia) * NKB + ((2 + woff) & (NKB - 1))) * 64 + lane) * 8);

    #pragma unroll
    for (int kb = 0; kb < NKB; ++kb) {
        if ((kb % 3) == 0)      MLP_STEP(a0, kb)
        else if ((kb % 3) == 1) MLP_STEP(a1, kb)
        else                    MLP_STEP(a2, kb)
    }
    __syncthreads();   // all reads done before in-place overwrite

    const int ch0 = wid * 64;
    #pragma unroll
    for (int ia = 0; ia < 4; ++ia) {
        int cb = ia * 16 + l4 * 4;
        float4 bv = *reinterpret_cast<const float4*>(bias + ch0 + cb);
        #pragma unroll
        for (int jb = 0; jb < 6; ++jb) {
            int pt = jb * 16 + l15;
            u32 pk0 = f2fp8x2(fmaxf(acc[ia][jb][0] + bv.x, 0.0f),
                              fmaxf(acc[ia][jb][1] + bv.y, 0.0f));
            u32 pk1 = f2fp8x2(fmaxf(acc[ia][jb][2] + bv.z, 0.0f),
                              fmaxf(acc[ia][jb][3] + bv.w, 0.0f));
            u32 word = pk0 | (pk1 << 16);
            int s = (ch0 + cb) >> 3;
            int sp = s ^ (pt & 7);
            *reinterpret_cast<u32*>(act + pt * 512 + sp * 8 + (cb & 4)) = word;
        }
    }
    __syncthreads();
}

__global__ __launch_bounds__(512, 2) void mlp_mfma_kernel(
    const float* __restrict__ f1, const float* __restrict__ f2,
    const float* __restrict__ kps1, const float* __restrict__ kps2,
    const float* __restrict__ scales1,
    const float* __restrict__ b1, const float* __restrict__ b2,
    const float* __restrict__ b3, const float* __restrict__ b4,
    const float* __restrict__ b5,
    const u8* __restrict__ wt8,
    const ull* __restrict__ rowfin, const ull* __restrict__ colfin,
    float* __restrict__ out)
{
    __shared__ __align__(16) unsigned char lds_raw[49152];   // 96 pts x 512 ch fp8
    u8* act = lds_raw;
    float* logf = reinterpret_cast<float*>(lds_raw);

    const int t = threadIdx.x;
    const int lane = t & 63, wid = t >> 6;
    const int base = blockIdx.x * 96;
    const int b = base / NN;
    const int n0 = base % NN;

    // stage concat(f1[n], f2[match12[n]]) as fp8, swizzled; 384 active threads
    if (t < 384) {
        const int pt = t >> 2, seg = t & 3;   // 4 segs * 32 dims
        const int n = n0 + pt;
        ull rm = rowfin[(size_t)b * NN + n];
        const int m = (int)(~(u32)(rm & 0xffffffffULL));
        const float* src = (seg < 2)
            ? (f1 + ((size_t)b * NN + n) * DD + seg * 32)
            : (f2 + ((size_t)b * NN + m) * DD + (seg - 2) * 32);
        #pragma unroll
        for (int q8 = 0; q8 < 4; ++q8) {
            float4 v0 = *reinterpret_cast<const float4*>(src + q8 * 8);
            float4 v1 = *reinterpret_cast<const float4*>(src + q8 * 8 + 4);
            ull w64 = (ull)f2fp8x2(v0.x, v0.y)
                    | ((ull)f2fp8x2(v0.z, v0.w) << 16)
                    | ((ull)f2fp8x2(v1.x, v1.y) << 32)
                    | ((ull)f2fp8x2(v1.z, v1.w) << 48);
            int s = seg * 4 + q8;
            int sp = s ^ (pt & 7);
            *reinterpret_cast<ull*>(act + pt * 512 + sp * 8) = w64;
        }
    }
    __syncthreads();

    mlp_layer8<128>(act, wt8 + WT1_OFF, b1, lane, wid);
    mlp_layer8<512>(act, wt8 + WT2_OFF, b2, lane, wid);
    mlp_layer8<512>(act, wt8 + WT3_OFF, b3, lane, wid);
    mlp_layer8<512>(act, wt8 + WT4_OFF, b4, lane, wid);

    // layer 5: 512 -> 64, no relu; waves 0-3 handle 16 out-ch each (staggered)
    {
        const int l15 = lane & 15, l4 = lane >> 4;
        floatx4 acc5[6];
        #pragma unroll
        for (int jb = 0; jb < 6; ++jb) acc5[jb] = (floatx4)(0.0f);
        if (wid < 4) {
            const int woff5 = (wid * 4) & 15;
            long a_cur = *reinterpret_cast<const long*>(
                wt8 + WT5_OFF + (((size_t)wid * 16 + woff5) * 64 + lane) * 8);
            long a_nxt;
            #pragma unroll
            for (int kb = 0; kb < 16; ++kb) {
                const int kb2 = (kb + woff5) & 15;
                if (kb + 1 < 16) {
                    const int kbn = (kb + 1 + woff5) & 15;
                    a_nxt = *reinterpret_cast<const long*>(
                        wt8 + WT5_OFF + (((size_t)wid * 16 + kbn) * 64 + lane) * 8);
                }
                __builtin_amdgcn_s_setprio(1);
                #pragma unroll
                for (int jb = 0; jb < 6; ++jb) {
                    const int pt = jb * 16 + l15;
                    const int sp = (kb2 * 4 + l4) ^ (pt & 7);
                    long bfr = *reinterpret_cast<const long*>(act + pt * 512 + sp * 8);
                    acc5[jb] = __builtin_amdgcn_mfma_f32_16x16x32_fp8_fp8(
                        a_cur, bfr, acc5[jb], 0, 0, 0);
                }
                __builtin_amdgcn_s_setprio(0);
                if (kb + 1 < 16) a_cur = a_nxt;
            }
        }
        __syncthreads();   // all act reads done; lds_raw becomes logits f32
        if (wid < 4) {
            int cb = wid * 16 + l4 * 4;
            float4 bv = *reinterpret_cast<const float4*>(b5 + cb);
            #pragma unroll
            for (int jb = 0; jb < 6; ++jb) {
                int pt = jb * 16 + l15;
                float4 o;
                o.x = acc5[jb][0] + bv.x;
                o.y = acc5[jb][1] + bv.y;
                o.z = acc5[jb][2] + bv.z;
                o.w = acc5[jb][3] + bv.w;
                *reinterpret_cast<float4*>(&logf[pt * 68 + cb]) = o;
            }
        }
        __syncthreads();
    }

    if (t < 96) {
        const int pt = t;
        const int n = n0 + pt;
        const float* lrow = &logf[pt * 68];
        float mx = -1e30f;
        #pragma unroll 8
        for (int j = 0; j < OUTD; ++j) mx = fmaxf(mx, 3.0f * lrow[j]);
        float s = 0.0f, cx = 0.0f, cy = 0.0f;
        #pragma unroll 8
        for (int j = 0; j < OUTD; ++j) {
            float e = __expf(3.0f * lrow[j] - mx);
            s  += e;
            cx += e * (float)((j & 7) - 4);
            cy += e * (float)((j >> 3) - 4);
        }
        float conf = 1.0f / s;
        cx /= s; cy /= s;
        ull rm = rowfin[(size_t)b * NN + n];
        int m = (int)(~(u32)(rm & 0xffffffffULL));
        ull cm = colfin[(size_t)b * NN + m];
        int back = (int)(~(u32)(cm & 0xffffffffULL));
        bool mutual = (back == n);
        float sc = scales1[(size_t)b * NN + n];
        float x0 = kps1[((size_t)b * NN + n) * 2 + 0] + cx * sc;
        float y0 = kps1[((size_t)b * NN + n) * 2 + 1] + cy * sc;
        float x1 = kps2[((size_t)b * NN + m) * 2 + 0];
        float y1 = kps2[((size_t)b * NN + m) * 2 + 1];
        float* mt = out + ((size_t)b * NN + n) * 4;
        mt[0] = x0; mt[1] = y0; mt[2] = x1; mt[3] = y1;
        out[(size_t)BB * NN * 4 + (size_t)b * NN + n] =
            (mutual && conf > 0.25f) ? 1.0f : 0.0f;
    }
}

extern "C" void kernel_launch(void* const* d_in, const int* in_sizes, int n_in,
                              void* d_out, int out_size, void* d_ws, size_t ws_size,
                              hipStream_t stream)
{
    const float* f1  = (const float*)d_in[0];
    const float* f2  = (const float*)d_in[1];
    const float* kp1 = (const float*)d_in[2];
    const float* kp2 = (const float*)d_in[3];
    const float* sc1 = (const float*)d_in[4];
    const float* w1  = (const float*)d_in[5];
    const float* b1  = (const float*)d_in[6];
    const float* w2  = (const float*)d_in[7];
    const float* b2  = (const float*)d_in[8];
    const float* w3  = (const float*)d_in[9];
    const float* b3  = (const float*)d_in[10];
    const float* w4  = (const float*)d_in[11];
    const float* b4  = (const float*)d_in[12];
    const float* w5  = (const float*)d_in[13];
    const float* b5  = (const float*)d_in[14];

    char* ws = (char*)d_ws;
    ull* rowfin = (ull*)(ws + OFF_ROWFIN);
    ull* colfin = (ull*)(ws + OFF_COLFIN);
    u8*  wt8    = (u8*)(ws + OFF_WT);
    u16* f1t    = (u16*)(ws + OFF_F1T);
    u16* f2t    = (u16*)(ws + OFF_F2T);
    u16* rbm    = (u16*)(ws + OFF_RBM);
    u16* cbm    = (u16*)(ws + OFF_CBM);
    int* cntR   = (int*)(ws + OFF_CNTR);
    int* cntC   = (int*)(ws + OFF_CNTC);
    int* listR  = (int*)(ws + OFF_LISTR);
    int* listC  = (int*)(ws + OFF_LISTC);
    float* out  = (float*)d_out;

    prep_kernel<<<(2 * BB * NN * DD) / 256, 256, 0, stream>>>(
        w1, w2, w3, w4, w5, f1, f2, wt8, f1t, f2t, rowfin, cntR);

    dim3 gS(48, 48, BB);
    simb_kernel<<<gS, 256, 0, stream>>>(f1t, f2t, rbm, cbm);

    dim3 gScan((BB * NN) / 256, 2);
    scan_kernel<<<gScan, 256, 0, stream>>>(rbm, cbm, cntR, cntC, listR, listC);

    dim3 gR(BB * 48, RSPLIT, 2);
    refine_kernel<<<gR, 256, 0, stream>>>(f1, f2, cntR, cntC, listR, listC,
                                          rowfin, colfin);

    mlp_mfma_kernel<<<(BB * NN) / 96, 512, 0, stream>>>(
        f1, f2, kp1, kp2, sc1, b1, b2, b3, b4, b5, wt8, rowfin, colfin, out);
}

// Round 16
// 132.082 us; speedup vs baseline: 1.4640x; 1.4640x over previous
//
#include <hip/hip_runtime.h>
#include <cstddef>
#include <cstdint>

#define BB 4
#define NN 6144
#define DD 64
#define HID 512
#define OUTD 64
#define CAP 512
#define RSPLIT 2

typedef unsigned long long ull;
typedef unsigned int u32;
typedef unsigned short u16;
typedef unsigned char u8;
typedef __attribute__((ext_vector_type(8))) short short8_t;
typedef __attribute__((ext_vector_type(4))) float floatx4;

// ---- ws layout (byte offsets) ----
#define OFF_ROWFIN 0
#define OFF_COLFIN 196608
#define OFF_WT     393216
#define OFF_F1T    2162688
#define OFF_F2T    5308416
#define OFF_RBM    8454144
#define OFF_CBM    10813440
#define OFF_CNTR   13172736
#define OFF_CNTC   13173504
#define OFF_LISTR  13174272
#define OFF_LISTC  13567488

#define WT1_OFF 0
#define WT2_OFF 65536
#define WT3_OFF 327680
#define WT4_OFF 589824
#define WT5_OFF 851968
#define WT_TOTAL 884736

__device__ __forceinline__ unsigned int fkey(float v) {
    unsigned int u = __float_as_uint(v);
    return (u & 0x80000000u) ? ~u : (u | 0x80000000u);
}

__device__ __forceinline__ float inv16(u32 k16) {
    u32 u = k16 << 16;
    return (u & 0x80000000u) ? __uint_as_float(u & 0x7fffffffu)
                             : __uint_as_float(~u);
}

__device__ __forceinline__ u16 f2bf(float f) {
    unsigned int u = __float_as_uint(f);
    u += 0x7FFFu + ((u >> 16) & 1u);
    return (u16)(u >> 16);
}

// two floats -> two fp8 (chip-native fp8; self-consistent with fp8 MFMA)
__device__ __forceinline__ u32 f2fp8x2(float a, float b) {
    return (u32)__builtin_amdgcn_cvt_pk_fp8_f32(a, b, 0, false) & 0xffffu;
}

// ---- prep: ws init + weights->fp8 tiled + feats->bf16 tiled ----
__global__ __launch_bounds__(256) void prep_kernel(
    const float* __restrict__ w1, const float* __restrict__ w2,
    const float* __restrict__ w3, const float* __restrict__ w4,
    const float* __restrict__ w5,
    const float* __restrict__ f1, const float* __restrict__ f2,
    u8* __restrict__ wt8, u16* __restrict__ f1t, u16* __restrict__ f2t,
    ull* __restrict__ finals, int* __restrict__ cnts)
{
    int idx = blockIdx.x * 256 + threadIdx.x;

    if (idx < 2 * BB * NN) finals[idx] = 0ULL;
    if (idx < 384) cnts[idx] = 0;

    if (idx < WT_TOTAL) {
        const float* w; u8* o; int K, nsh, li;
        if (idx < 65536)        { w = w1; o = wt8 + WT1_OFF; K = 128; nsh = 9; li = idx; }
        else if (idx < 327680)  { w = w2; o = wt8 + WT2_OFF; K = 512; nsh = 9; li = idx - 65536; }
        else if (idx < 589824)  { w = w3; o = wt8 + WT3_OFF; K = 512; nsh = 9; li = idx - 327680; }
        else if (idx < 851968)  { w = w4; o = wt8 + WT4_OFF; K = 512; nsh = 9; li = idx - 589824; }
        else                    { w = w5; o = wt8 + WT5_OFF; K = 512; nsh = 6; li = idx - 851968; }
        int k = li >> nsh;
        int n = li & ((1 << nsh) - 1);
        u8 v = (u8)(f2fp8x2(w[li], 0.0f) & 0xff);
        int lane = (n & 15) | (((k >> 3) & 3) << 4);
        o[(((size_t)(n >> 4) * (K >> 5) + (k >> 5)) * 64 + lane) * 8 + (k & 7)] = v;
    }

    {
        const int TE = BB * NN * DD;
        const float* src; u16* dst; int e;
        if (idx < TE) { src = f1; dst = f1t; e = idx; }
        else          { src = f2; dst = f2t; e = idx - TE; }
        int k  = e & 63;
        int rn = e >> 6;
        int b  = rn / NN;
        int r  = rn - b * NN;
        int R  = r >> 7, rb = (r >> 4) & 7;
        int kb = k >> 5, lane = (r & 15) | (((k >> 3) & 3) << 4), j = k & 7;
        dst[(size_t)(b * 48 + R) * 8192 + ((rb * 2 + kb) * 64 + lane) * 8 + j] = f2bf(src[e]);
    }
}

// ---- Kernel A: bf16 MFMA sim, 128x128 tile, 4 waves x (32 rows x 128 cols),
//      wave-local row-max, LDS col-merge; TRANSPOSED maxima [b][C][n] ----
__global__ __launch_bounds__(256, 4) void simb_kernel(
    const u16* __restrict__ f1t, const u16* __restrict__ f2t,
    u16* __restrict__ rbm, u16* __restrict__ cbm)
{
    __shared__ __align__(16) u16 sA[8192];
    __shared__ __align__(16) u16 sB[8192];
    __shared__ float cv[4][128];
    const int R = blockIdx.x, C = blockIdx.y, b = blockIdx.z;
    const int t = threadIdx.x, lane = t & 63, w = t >> 6;
    const int l15 = lane & 15, l4 = lane >> 4;

    const u16* Ag = f1t + (size_t)(b * 48 + R) * 8192;
    const u16* Bg = f2t + (size_t)(b * 48 + C) * 8192;

    #pragma unroll
    for (int rnd = 0; rnd < 4; ++rnd) {
        int c = rnd * 256 + t;
        *reinterpret_cast<uint4*>(&sA[c * 8]) = *reinterpret_cast<const uint4*>(Ag + c * 8);
        *reinterpret_cast<uint4*>(&sB[c * 8]) = *reinterpret_cast<const uint4*>(Bg + c * 8);
    }
    __syncthreads();

    floatx4 acc[2][8];
    #pragma unroll
    for (int i = 0; i < 2; ++i)
        #pragma unroll
        for (int j = 0; j < 8; ++j) acc[i][j] = (floatx4)(0.0f);

    #pragma unroll
    for (int kb = 0; kb < 2; ++kb) {
        short8_t afr[2];
        #pragma unroll
        for (int i = 0; i < 2; ++i)
            afr[i] = *reinterpret_cast<const short8_t*>(
                &sA[(((2 * w + i) * 2 + kb) * 64 + lane) * 8]);
        #pragma unroll
        for (int j = 0; j < 8; ++j) {
            short8_t bfr = *reinterpret_cast<const short8_t*>(
                &sB[((j * 2 + kb) * 64 + lane) * 8]);
            #pragma unroll
            for (int i = 0; i < 2; ++i)
                acc[i][j] = __builtin_amdgcn_mfma_f32_16x16x32_bf16(
                    afr[i], bfr, acc[i][j], 0, 0, 0);
        }
    }

    // row-max: fully wave-local (all 128 cols in-wave); 4-shfl over l15
    #pragma unroll
    for (int i = 0; i < 2; ++i) {
        #pragma unroll
        for (int reg = 0; reg < 4; ++reg) {
            float v = acc[i][0][reg];
            #pragma unroll
            for (int j = 1; j < 8; ++j) v = fmaxf(v, acc[i][j][reg]);
            v = fmaxf(v, __shfl_xor(v, 1));
            v = fmaxf(v, __shfl_xor(v, 2));
            v = fmaxf(v, __shfl_xor(v, 4));
            v = fmaxf(v, __shfl_xor(v, 8));
            if (l15 == 0) {
                int row = R * 128 + w * 32 + i * 16 + l4 * 4 + reg;
                rbm[((size_t)b * 48 + C) * NN + row] = (u16)(fkey(v) >> 16);
            }
        }
    }

    // col-max: in-lane over (i,reg), 2-shfl over l4, then 4-wave LDS merge
    #pragma unroll
    for (int j = 0; j < 8; ++j) {
        float v = acc[0][j][0];
        #pragma unroll
        for (int i = 0; i < 2; ++i)
            #pragma unroll
            for (int reg = 0; reg < 4; ++reg) v = fmaxf(v, acc[i][j][reg]);
        v = fmaxf(v, __shfl_xor(v, 16));
        v = fmaxf(v, __shfl_xor(v, 32));
        if (l4 == 0) cv[w][j * 16 + l15] = v;
    }
    __syncthreads();
    if (t < 128) {
        float v = fmaxf(fmaxf(cv[0][t], cv[1][t]), fmaxf(cv[2][t], cv[3][t]));
        cbm[((size_t)b * 48 + R) * NN + C * 128 + t] = (u16)(fkey(v) >> 16);
    }
}

// ---- scan (merged row/col via blockIdx.y): transposed bm reads,
//      block-aggregated candidate append ----
__global__ __launch_bounds__(256) void scan_kernel(
    const u16* __restrict__ rbm, const u16* __restrict__ cbm,
    int* __restrict__ cntR, int* __restrict__ cntC,
    int* __restrict__ listR, int* __restrict__ listC)
{
    const u16* bm = blockIdx.y ? cbm : rbm;
    int* cnt  = blockIdx.y ? cntC : cntR;
    int* list = blockIdx.y ? listC : listR;

    __shared__ int lcnt[48];
    __shared__ int lbase[48];
    const int t = threadIdx.x;
    if (t < 48) lcnt[t] = 0;
    const int idx = blockIdx.x * 256 + t;
    const int b = (blockIdx.x * 256) / NN;
    const int n = idx - b * NN;

    u16 ks[48];
    #pragma unroll
    for (int c = 0; c < 48; ++c)
        ks[c] = bm[((size_t)b * 48 + c) * NN + n];

    u16 mx = 0;
    #pragma unroll
    for (int c = 0; c < 48; ++c) mx = ks[c] > mx ? ks[c] : mx;
    // margin: worst-case bf16 sim error |S~-S| <= 2^-8 * sum|a_k b_k| <= 0.0039
    // (round-to-nearest f2bf, unit vectors); listing the true block needs
    // margin >= 2*0.0039 = 0.0078; 0.010 gives 28% cushion.
    float thr = inv16(mx) - 0.010f;
    u32 m0 = 0, m1 = 0;
    #pragma unroll
    for (int c = 0; c < 48; ++c) {
        if (inv16((u32)ks[c] + 1) >= thr) {
            if (c < 32) m0 |= 1u << c; else m1 |= 1u << (c - 32);
        }
    }
    __syncthreads();
    {
        u32 a = m0;
        while (a) { int c = __builtin_ctz(a); a &= a - 1; atomicAdd(&lcnt[c], 1); }
        a = m1;
        while (a) { int c = 32 + __builtin_ctz(a); a &= a - 1; atomicAdd(&lcnt[c], 1); }
    }
    __syncthreads();
    if (t < 48) { lbase[t] = atomicAdd(&cnt[b * 48 + t], lcnt[t]); lcnt[t] = 0; }
    __syncthreads();
    {
        u32 a = m0;
        while (a) {
            int c = __builtin_ctz(a); a &= a - 1;
            int pos = lbase[c] + atomicAdd(&lcnt[c], 1);
            if (pos < CAP) list[(b * 48 + c) * CAP + pos] = n;
        }
        a = m1;
        while (a) {
            int c = 32 + __builtin_ctz(a); a &= a - 1;
            int pos = lbase[c] + atomicAdd(&lcnt[c], 1);
            if (pos < CAP) list[(b * 48 + c) * CAP + pos] = n;
        }
    }
}

// ---- exact fp32 refine v4: LDS targets (v14 conflict-free layout) +
//      LDS queries, 4q x 8t register blocking, 64-query iters ----
__global__ __launch_bounds__(256, 2) void refine_kernel(
    const float* __restrict__ f1, const float* __restrict__ f2,
    const int* __restrict__ cntR, const int* __restrict__ cntC,
    const int* __restrict__ listR, const int* __restrict__ listC,
    ull* __restrict__ rowfin, ull* __restrict__ colfin)
{
    const float* qfeat = blockIdx.z ? f2 : f1;
    const float* tfeat = blockIdx.z ? f1 : f2;
    const int* cnt  = blockIdx.z ? cntC : cntR;
    const int* list = blockIdx.z ? listC : listR;
    ull* fin = blockIdx.z ? colfin : rowfin;

    const int b = blockIdx.x / 48;
    const int C = blockIdx.x - b * 48;
    const int sub = blockIdx.y;
    int n_items = cnt[b * 48 + C];
    if (n_items > CAP) n_items = CAP;
    int chunk = (n_items + RSPLIT - 1) / RSPLIT;
    int lo = sub * chunk;
    int hi = lo + chunk; if (hi > n_items) hi = n_items;
    if (lo >= hi) return;

    __shared__ float s2f[128 * 68];   // targets, v14 layout (0 conflicts)
    __shared__ float sq[64 * 68];     // 64 staged query rows
    const int t = threadIdx.x;
    const int cg = t & 15;            // target col group (8 targets: cg+16*c8)
    const int rs = t >> 4;            // query group (4 queries: rs*4+j)
    const float* tb = tfeat + ((size_t)b * NN + C * 128) * 64;
    #pragma unroll
    for (int p = 0; p < 8; ++p) {
        int idx = p * 256 + t;
        int row = idx >> 4, c4 = idx & 15;
        *reinterpret_cast<float4*>(&s2f[row * 68 + c4 * 4]) =
            *reinterpret_cast<const float4*>(tb + row * 64 + c4 * 4);
    }
    __syncthreads();
    const int* mylist = list + (b * 48 + C) * CAP;

    for (int base = lo; base < hi; base += 64) {
        __syncthreads();   // protect sq reuse from previous iteration
        #pragma unroll
        for (int s = 0; s < 4; ++s) {
            int fi = s * 256 + t;           // 1024 float4 = 64 rows x 16
            int q = fi >> 4, c4 = fi & 15;
            int lq = base + q;
            int nn = (lq < hi) ? mylist[lq] : mylist[lo];
            *reinterpret_cast<float4*>(&sq[q * 68 + c4 * 4]) =
                *reinterpret_cast<const float4*>(
                    qfeat + ((size_t)b * NN + nn) * 64 + c4 * 4);
        }
        __syncthreads();

        float acc[4][8];   // [query j][target c8]
        #pragma unroll
        for (int j = 0; j < 4; ++j)
            #pragma unroll
            for (int c8 = 0; c8 < 8; ++c8) acc[j][c8] = 0.0f;

        #pragma unroll 4
        for (int kq = 0; kq < 16; ++kq) {
            float4 qv[4];
            #pragma unroll
            for (int j = 0; j < 4; ++j)
                qv[j] = *reinterpret_cast<const float4*>(
                    &sq[(rs * 4 + j) * 68 + kq * 4]);
            #pragma unroll
            for (int c8 = 0; c8 < 8; ++c8) {
                float4 tv = *reinterpret_cast<const float4*>(
                    &s2f[(cg + 16 * c8) * 68 + kq * 4]);
                #pragma unroll
                for (int j = 0; j < 4; ++j) {
                    acc[j][c8] = fmaf(qv[j].x, tv.x, acc[j][c8]);
                    acc[j][c8] = fmaf(qv[j].y, tv.y, acc[j][c8]);
                    acc[j][c8] = fmaf(qv[j].z, tv.z, acc[j][c8]);
                    acc[j][c8] = fmaf(qv[j].w, tv.w, acc[j][c8]);
                }
            }
        }

        // per query: best over my 8 targets, then 4-step shfl over cg lanes
        #pragma unroll
        for (int j = 0; j < 4; ++j) {
            int lq = base + rs * 4 + j;
            bool valid = lq < hi;
            float bv = acc[j][0]; int bt = cg;
            #pragma unroll
            for (int c8 = 1; c8 < 8; ++c8)
                if (acc[j][c8] > bv) { bv = acc[j][c8]; bt = cg + 16 * c8; }
            ull pk = ((ull)fkey(bv) << 32) | (u32)(~(u32)(C * 128 + bt));
            ull qq;
            qq = __shfl_xor(pk, 1); pk = pk > qq ? pk : qq;
            qq = __shfl_xor(pk, 2); pk = pk > qq ? pk : qq;
            qq = __shfl_xor(pk, 4); pk = pk > qq ? pk : qq;
            qq = __shfl_xor(pk, 8); pk = pk > qq ? pk : qq;
            if (cg == 0 && valid) {
                int n = mylist[lq];
                atomicMax(&fin[(size_t)b * NN + n], pk);
            }
        }
    }
}

// ---- Kernel B: fp8 MFMA MLP, 96 pts/block, grid=256 (1 block/CU),
//      512 thr / 8 waves, 64ch/wave, stagger + setprio + 3-buf prefetch ----

#define MLP_STEP(BUF, KB)                                                        \
    {                                                                            \
        const int kb2 = ((KB) + woff) & (NKB - 1);                               \
        __builtin_amdgcn_s_setprio(1);                                           \
        _Pragma("unroll")                                                        \
        for (int jb = 0; jb < 6; ++jb) {                                         \
            const int pt = jb * 16 + l15;                                        \
            const int sp = (kb2 * 4 + l4) ^ (pt & 7);                            \
            long bfr = *reinterpret_cast<const long*>(act + pt * 512 + sp * 8);  \
            _Pragma("unroll")                                                    \
            for (int ia = 0; ia < 4; ++ia)                                       \
                acc[ia][jb] = __builtin_amdgcn_mfma_f32_16x16x32_fp8_fp8(        \
                    BUF[ia], bfr, acc[ia][jb], 0, 0, 0);                         \
        }                                                                        \
        __builtin_amdgcn_s_setprio(0);                                           \
        if ((KB) + 3 < NKB) {                                                    \
            const int kbp = ((KB) + 3 + woff) & (NKB - 1);                       \
            _Pragma("unroll")                                                    \
            for (int ia = 0; ia < 4; ++ia)                                       \
                BUF[ia] = *reinterpret_cast<const long*>(                        \
                    wt8 + (((size_t)(chBlk0 + ia) * NKB + kbp) * 64 + lane) * 8);\
        }                                                                        \
    }

template<int K>
__device__ __forceinline__ void mlp_layer8(
    u8* act, const u8* __restrict__ wt8,
    const float* __restrict__ bias, int lane, int wid)
{
    constexpr int NKB = K / 32;
    floatx4 acc[4][6];
    #pragma unroll
    for (int ia = 0; ia < 4; ++ia)
        #pragma unroll
        for (int jb = 0; jb < 6; ++jb)
            acc[ia][jb] = (floatx4)(0.0f);

    const int l15 = lane & 15, l4 = lane >> 4;
    const int chBlk0 = wid * 4;               // (wid*64)/16
    const int woff = (wid * 2) & (NKB - 1);   // per-wave kb stagger

    long a0[4], a1[4], a2[4];
    #pragma unroll
    for (int ia = 0; ia < 4; ++ia)
        a0[ia] = *reinterpret_cast<const long*>(
            wt8 + (((size_t)(chBlk0 + ia) * NKB + ((0 + woff) & (NKB - 1))) * 64 + lane) * 8);
    #pragma unroll
    for (int ia = 0; ia < 4; ++ia)
        a1[ia] = *reinterpret_cast<const long*>(
            wt8 + (((size_t)(chBlk0 + ia) * NKB + ((1 + woff) & (NKB - 1))) * 64 + lane) * 8);
    #pragma unroll
    for (int ia = 0; ia < 4; ++ia)
        a2[ia] = *reinterpret_cast<const long*>(
            wt8 + (((size_t)(chBlk0 + ia) * NKB + ((2 + woff) & (NKB - 1))) * 64 + lane) * 8);

    #pragma unroll
    for (int kb = 0; kb < NKB; ++kb) {
        if ((kb % 3) == 0)      MLP_STEP(a0, kb)
        else if ((kb % 3) == 1) MLP_STEP(a1, kb)
        else                    MLP_STEP(a2, kb)
    }
    __syncthreads();   // all reads done before in-place overwrite

    const int ch0 = wid * 64;
    #pragma unroll
    for (int ia = 0; ia < 4; ++ia) {
        int cb = ia * 16 + l4 * 4;
        float4 bv = *reinterpret_cast<const float4*>(bias + ch0 + cb);
        #pragma unroll
        for (int jb = 0; jb < 6; ++jb) {
            int pt = jb * 16 + l15;
            u32 pk0 = f2fp8x2(fmaxf(acc[ia][jb][0] + bv.x, 0.0f),
                              fmaxf(acc[ia][jb][1] + bv.y, 0.0f));
            u32 pk1 = f2fp8x2(fmaxf(acc[ia][jb][2] + bv.z, 0.0f),
                              fmaxf(acc[ia][jb][3] + bv.w, 0.0f));
            u32 word = pk0 | (pk1 << 16);
            int s = (ch0 + cb) >> 3;
            int sp = s ^ (pt & 7);
            *reinterpret_cast<u32*>(act + pt * 512 + sp * 8 + (cb & 4)) = word;
        }
    }
    __syncthreads();
}

__global__ __launch_bounds__(512, 2) void mlp_mfma_kernel(
    const float* __restrict__ f1, const float* __restrict__ f2,
    const float* __restrict__ kps1, const float* __restrict__ kps2,
    const float* __restrict__ scales1,
    const float* __restrict__ b1, const float* __restrict__ b2,
    const float* __restrict__ b3, const float* __restrict__ b4,
    const float* __restrict__ b5,
    const u8* __restrict__ wt8,
    const ull* __restrict__ rowfin, const ull* __restrict__ colfin,
    float* __restrict__ out)
{
    __shared__ __align__(16) unsigned char lds_raw[49152];   // 96 pts x 512 ch fp8
    u8* act = lds_raw;
    float* logf = reinterpret_cast<float*>(lds_raw);

    const int t = threadIdx.x;
    const int lane = t & 63, wid = t >> 6;
    const int base = blockIdx.x * 96;
    const int b = base / NN;
    const int n0 = base % NN;

    // stage concat(f1[n], f2[match12[n]]) as fp8, swizzled; 384 active threads
    if (t < 384) {
        const int pt = t >> 2, seg = t & 3;   // 4 segs * 32 dims
        const int n = n0 + pt;
        ull rm = rowfin[(size_t)b * NN + n];
        const int m = (int)(~(u32)(rm & 0xffffffffULL));
        const float* src = (seg < 2)
            ? (f1 + ((size_t)b * NN + n) * DD + seg * 32)
            : (f2 + ((size_t)b * NN + m) * DD + (seg - 2) * 32);
        #pragma unroll
        for (int q8 = 0; q8 < 4; ++q8) {
            float4 v0 = *reinterpret_cast<const float4*>(src + q8 * 8);
            float4 v1 = *reinterpret_cast<const float4*>(src + q8 * 8 + 4);
            ull w64 = (ull)f2fp8x2(v0.x, v0.y)
                    | ((ull)f2fp8x2(v0.z, v0.w) << 16)
                    | ((ull)f2fp8x2(v1.x, v1.y) << 32)
                    | ((ull)f2fp8x2(v1.z, v1.w) << 48);
            int s = seg * 4 + q8;
            int sp = s ^ (pt & 7);
            *reinterpret_cast<ull*>(act + pt * 512 + sp * 8) = w64;
        }
    }
    __syncthreads();

    mlp_layer8<128>(act, wt8 + WT1_OFF, b1, lane, wid);
    mlp_layer8<512>(act, wt8 + WT2_OFF, b2, lane, wid);
    mlp_layer8<512>(act, wt8 + WT3_OFF, b3, lane, wid);
    mlp_layer8<512>(act, wt8 + WT4_OFF, b4, lane, wid);

    // layer 5: 512 -> 64, no relu; waves 0-3 handle 16 out-ch each (staggered)
    {
        const int l15 = lane & 15, l4 = lane >> 4;
        floatx4 acc5[6];
        #pragma unroll
        for (int jb = 0; jb < 6; ++jb) acc5[jb] = (floatx4)(0.0f);
        if (wid < 4) {
            const int woff5 = (wid * 4) & 15;
            long a_cur = *reinterpret_cast<const long*>(
                wt8 + WT5_OFF + (((size_t)wid * 16 + woff5) * 64 + lane) * 8);
            long a_nxt;
            #pragma unroll
            for (int kb = 0; kb < 16; ++kb) {
                const int kb2 = (kb + woff5) & 15;
                if (kb + 1 < 16) {
                    const int kbn = (kb + 1 + woff5) & 15;
                    a_nxt = *reinterpret_cast<const long*>(
                        wt8 + WT5_OFF + (((size_t)wid * 16 + kbn) * 64 + lane) * 8);
                }
                __builtin_amdgcn_s_setprio(1);
                #pragma unroll
                for (int jb = 0; jb < 6; ++jb) {
                    const int pt = jb * 16 + l15;
                    const int sp = (kb2 * 4 + l4) ^ (pt & 7);
                    long bfr = *reinterpret_cast<const long*>(act + pt * 512 + sp * 8);
                    acc5[jb] = __builtin_amdgcn_mfma_f32_16x16x32_fp8_fp8(
                        a_cur, bfr, acc5[jb], 0, 0, 0);
                }
                __builtin_amdgcn_s_setprio(0);
                if (kb + 1 < 16) a_cur = a_nxt;
            }
        }
        __syncthreads();   // all act reads done; lds_raw becomes logits f32
        if (wid < 4) {
            int cb = wid * 16 + l4 * 4;
            float4 bv = *reinterpret_cast<const float4*>(b5 + cb);
            #pragma unroll
            for (int jb = 0; jb < 6; ++jb) {
                int pt = jb * 16 + l15;
                float4 o;
                o.x = acc5[jb][0] + bv.x;
                o.y = acc5[jb][1] + bv.y;
                o.z = acc5[jb][2] + bv.z;
                o.w = acc5[jb][3] + bv.w;
                *reinterpret_cast<float4*>(&logf[pt * 68 + cb]) = o;
            }
        }
        __syncthreads();
    }

    if (t < 96) {
        const int pt = t;
        const int n = n0 + pt;
        const float* lrow = &logf[pt * 68];
        float mx = -1e30f;
        #pragma unroll 8
        for (int j = 0; j < OUTD; ++j) mx = fmaxf(mx, 3.0f * lrow[j]);
        float s = 0.0f, cx = 0.0f, cy = 0.0f;
        #pragma unroll 8
        for (int j = 0; j < OUTD; ++j) {
            float e = __expf(3.0f * lrow[j] - mx);
            s  += e;
            cx += e * (float)((j & 7) - 4);
            cy += e * (float)((j >> 3) - 4);
        }
        float conf = 1.0f / s;
        cx /= s; cy /= s;
        ull rm = rowfin[(size_t)b * NN + n];
        int m = (int)(~(u32)(rm & 0xffffffffULL));
        ull cm = colfin[(size_t)b * NN + m];
        int back = (int)(~(u32)(cm & 0xffffffffULL));
        bool mutual = (back == n);
        float sc = scales1[(size_t)b * NN + n];
        float x0 = kps1[((size_t)b * NN + n) * 2 + 0] + cx * sc;
        float y0 = kps1[((size_t)b * NN + n) * 2 + 1] + cy * sc;
        float x1 = kps2[((size_t)b * NN + m) * 2 + 0];
        float y1 = kps2[((size_t)b * NN + m) * 2 + 1];
        float* mt = out + ((size_t)b * NN + n) * 4;
        mt[0] = x0; mt[1] = y0; mt[2] = x1; mt[3] = y1;
        out[(size_t)BB * NN * 4 + (size_t)b * NN + n] =
            (mutual && conf > 0.25f) ? 1.0f : 0.0f;
    }
}

extern "C" void kernel_launch(void* const* d_in, const int* in_sizes, int n_in,
                              void* d_out, int out_size, void* d_ws, size_t ws_size,
                              hipStream_t stream)
{
    const float* f1  = (const float*)d_in[0];
    const float* f2  = (const float*)d_in[1];
    const float* kp1 = (const float*)d_in[2];
    const float* kp2 = (const float*)d_in[3];
    const float* sc1 = (const float*)d_in[4];
    const float* w1  = (const float*)d_in[5];
    const float* b1  = (const float*)d_in[6];
    const float* w2  = (const float*)d_in[7];
    const float* b2  = (const float*)d_in[8];
    const float* w3  = (const float*)d_in[9];
    const float* b3  = (const float*)d_in[10];
    const float* w4  = (const float*)d_in[11];
    const float* b4  = (const float*)d_in[12];
    const float* w5  = (const float*)d_in[13];
    const float* b5  = (const float*)d_in[14];

    char* ws = (char*)d_ws;
    ull* rowfin = (ull*)(ws + OFF_ROWFIN);
    ull* colfin = (ull*)(ws + OFF_COLFIN);
    u8*  wt8    = (u8*)(ws + OFF_WT);
    u16* f1t    = (u16*)(ws + OFF_F1T);
    u16* f2t    = (u16*)(ws + OFF_F2T);
    u16* rbm    = (u16*)(ws + OFF_RBM);
    u16* cbm    = (u16*)(ws + OFF_CBM);
    int* cntR   = (int*)(ws + OFF_CNTR);
    int* cntC   = (int*)(ws + OFF_CNTC);
    int* listR  = (int*)(ws + OFF_LISTR);
    int* listC  = (int*)(ws + OFF_LISTC);
    float* out  = (float*)d_out;

    prep_kernel<<<(2 * BB * NN * DD) / 256, 256, 0, stream>>>(
        w1, w2, w3, w4, w5, f1, f2, wt8, f1t, f2t, rowfin, cntR);

    dim3 gS(48, 48, BB);
    simb_kernel<<<gS, 256, 0, stream>>>(f1t, f2t, rbm, cbm);

    dim3 gScan((BB * NN) / 256, 2);
    scan_kernel<<<gScan, 256, 0, stream>>>(rbm, cbm, cntR, cntC, listR, listC);

    dim3 gR(BB * 48, RSPLIT, 2);
    refine_kernel<<<gR, 256, 0, stream>>>(f1, f2, cntR, cntC, listR, listC,
                                          rowfin, colfin);

    mlp_mfma_kernel<<<(BB * NN) / 96, 512, 0, stream>>>(
        f1, f2, kp1, kp2, sc1, b1, b2, b3, b4, b5, wt8, rowfin, colfin, out);
}

// Round 17
// 131.506 us; speedup vs baseline: 1.4704x; 1.0044x over previous
//
#include <hip/hip_runtime.h>
#include <cstddef>
#include <cstdint>

#define BB 4
#define NN 6144
#define DD 64
#define HID 512
#define OUTD 64
#define CAP 512
#define RSPLIT 2

typedef unsigned long long ull;
typedef unsigned int u32;
typedef unsigned short u16;
typedef unsigned char u8;
typedef __attribute__((ext_vector_type(8))) short short8_t;
typedef __attribute__((ext_vector_type(4))) float floatx4;

// ---- ws layout (byte offsets) ----
#define OFF_ROWFIN 0
#define OFF_COLFIN 196608
#define OFF_WT     393216
#define OFF_F1T    2162688
#define OFF_F2T    5308416
#define OFF_RBM    8454144
#define OFF_CBM    10813440
#define OFF_CNTR   13172736
#define OFF_CNTC   13173504
#define OFF_LISTR  13174272
#define OFF_LISTC  13567488

#define WT1_OFF 0
#define WT2_OFF 65536
#define WT3_OFF 327680
#define WT4_OFF 589824
#define WT5_OFF 851968
#define WT_TOTAL 884736

__device__ __forceinline__ unsigned int fkey(float v) {
    unsigned int u = __float_as_uint(v);
    return (u & 0x80000000u) ? ~u : (u | 0x80000000u);
}

__device__ __forceinline__ float inv16(u32 k16) {
    u32 u = k16 << 16;
    return (u & 0x80000000u) ? __uint_as_float(u & 0x7fffffffu)
                             : __uint_as_float(~u);
}

__device__ __forceinline__ u16 f2bf(float f) {
    unsigned int u = __float_as_uint(f);
    u += 0x7FFFu + ((u >> 16) & 1u);
    return (u16)(u >> 16);
}

// two floats -> two fp8 (chip-native fp8; self-consistent with fp8 MFMA)
__device__ __forceinline__ u32 f2fp8x2(float a, float b) {
    return (u32)__builtin_amdgcn_cvt_pk_fp8_f32(a, b, 0, false) & 0xffffu;
}

// ---- prep: ws init + weights->fp8 tiled + feats->bf16 tiled ----
__global__ __launch_bounds__(256) void prep_kernel(
    const float* __restrict__ w1, const float* __restrict__ w2,
    const float* __restrict__ w3, const float* __restrict__ w4,
    const float* __restrict__ w5,
    const float* __restrict__ f1, const float* __restrict__ f2,
    u8* __restrict__ wt8, u16* __restrict__ f1t, u16* __restrict__ f2t,
    ull* __restrict__ finals, int* __restrict__ cnts)
{
    int idx = blockIdx.x * 256 + threadIdx.x;

    if (idx < 2 * BB * NN) finals[idx] = 0ULL;
    if (idx < 384) cnts[idx] = 0;

    if (idx < WT_TOTAL) {
        const float* w; u8* o; int K, nsh, li;
        if (idx < 65536)        { w = w1; o = wt8 + WT1_OFF; K = 128; nsh = 9; li = idx; }
        else if (idx < 327680)  { w = w2; o = wt8 + WT2_OFF; K = 512; nsh = 9; li = idx - 65536; }
        else if (idx < 589824)  { w = w3; o = wt8 + WT3_OFF; K = 512; nsh = 9; li = idx - 327680; }
        else if (idx < 851968)  { w = w4; o = wt8 + WT4_OFF; K = 512; nsh = 9; li = idx - 589824; }
        else                    { w = w5; o = wt8 + WT5_OFF; K = 512; nsh = 6; li = idx - 851968; }
        int k = li >> nsh;
        int n = li & ((1 << nsh) - 1);
        u8 v = (u8)(f2fp8x2(w[li], 0.0f) & 0xff);
        int lane = (n & 15) | (((k >> 3) & 3) << 4);
        o[(((size_t)(n >> 4) * (K >> 5) + (k >> 5)) * 64 + lane) * 8 + (k & 7)] = v;
    }

    {
        const int TE = BB * NN * DD;
        const float* src; u16* dst; int e;
        if (idx < TE) { src = f1; dst = f1t; e = idx; }
        else          { src = f2; dst = f2t; e = idx - TE; }
        int k  = e & 63;
        int rn = e >> 6;
        int b  = rn / NN;
        int r  = rn - b * NN;
        int R  = r >> 7, rb = (r >> 4) & 7;
        int kb = k >> 5, lane = (r & 15) | (((k >> 3) & 3) << 4), j = k & 7;
        dst[(size_t)(b * 48 + R) * 8192 + ((rb * 2 + kb) * 64 + lane) * 8 + j] = f2bf(src[e]);
    }
}

// ---- Kernel A v3: bf16 MFMA sim, NO LDS staging — fragments loaded directly
//      from global (coalesced 1KB wave-loads; B L1-shared, A L2-hot).
//      128x128 tile, 4 waves x (32 rows x 128 cols); TRANSPOSED maxima ----
__global__ __launch_bounds__(256, 4) void simb_kernel(
    const u16* __restrict__ f1t, const u16* __restrict__ f2t,
    u16* __restrict__ rbm, u16* __restrict__ cbm)
{
    __shared__ float cv[4][128];
    const int R = blockIdx.x, C = blockIdx.y, b = blockIdx.z;
    const int t = threadIdx.x, lane = t & 63, w = t >> 6;
    const int l15 = lane & 15, l4 = lane >> 4;

    const u16* At = f1t + (size_t)(b * 48 + R) * 8192;
    const u16* Bt = f2t + (size_t)(b * 48 + C) * 8192;

    // A fragments: wave's rows rb = 2w, 2w+1 (per-wave unique, coalesced)
    short8_t afr[2][2];
    #pragma unroll
    for (int i = 0; i < 2; ++i)
        #pragma unroll
        for (int kb = 0; kb < 2; ++kb)
            afr[i][kb] = *reinterpret_cast<const short8_t*>(
                At + ((2 * w + i) * 2 + kb) * 512 + lane * 8);

    floatx4 acc[2][8];
    #pragma unroll
    for (int i = 0; i < 2; ++i)
        #pragma unroll
        for (int j = 0; j < 8; ++j) acc[i][j] = (floatx4)(0.0f);

    // B fragments: shared by all 4 waves (L1); j+1 prefetch
    short8_t bc0 = *reinterpret_cast<const short8_t*>(Bt + lane * 8);
    short8_t bc1 = *reinterpret_cast<const short8_t*>(Bt + 512 + lane * 8);
    short8_t bn0, bn1;
    #pragma unroll
    for (int j = 0; j < 8; ++j) {
        if (j < 7) {
            bn0 = *reinterpret_cast<const short8_t*>(
                Bt + ((j + 1) * 2 + 0) * 512 + lane * 8);
            bn1 = *reinterpret_cast<const short8_t*>(
                Bt + ((j + 1) * 2 + 1) * 512 + lane * 8);
        }
        #pragma unroll
        for (int i = 0; i < 2; ++i)
            acc[i][j] = __builtin_amdgcn_mfma_f32_16x16x32_bf16(
                afr[i][0], bc0, acc[i][j], 0, 0, 0);
        #pragma unroll
        for (int i = 0; i < 2; ++i)
            acc[i][j] = __builtin_amdgcn_mfma_f32_16x16x32_bf16(
                afr[i][1], bc1, acc[i][j], 0, 0, 0);
        if (j < 7) { bc0 = bn0; bc1 = bn1; }
    }

    // row-max: fully wave-local (all 128 cols in-wave); 4-shfl over l15
    #pragma unroll
    for (int i = 0; i < 2; ++i) {
        #pragma unroll
        for (int reg = 0; reg < 4; ++reg) {
            float v = acc[i][0][reg];
            #pragma unroll
            for (int j = 1; j < 8; ++j) v = fmaxf(v, acc[i][j][reg]);
            v = fmaxf(v, __shfl_xor(v, 1));
            v = fmaxf(v, __shfl_xor(v, 2));
            v = fmaxf(v, __shfl_xor(v, 4));
            v = fmaxf(v, __shfl_xor(v, 8));
            if (l15 == 0) {
                int row = R * 128 + w * 32 + i * 16 + l4 * 4 + reg;
                rbm[((size_t)b * 48 + C) * NN + row] = (u16)(fkey(v) >> 16);
            }
        }
    }

    // col-max: in-lane over (i,reg), 2-shfl over l4, then 4-wave LDS merge
    #pragma unroll
    for (int j = 0; j < 8; ++j) {
        float v = acc[0][j][0];
        #pragma unroll
        for (int i = 0; i < 2; ++i)
            #pragma unroll
            for (int reg = 0; reg < 4; ++reg) v = fmaxf(v, acc[i][j][reg]);
        v = fmaxf(v, __shfl_xor(v, 16));
        v = fmaxf(v, __shfl_xor(v, 32));
        if (l4 == 0) cv[w][j * 16 + l15] = v;
    }
    __syncthreads();
    if (t < 128) {
        float v = fmaxf(fmaxf(cv[0][t], cv[1][t]), fmaxf(cv[2][t], cv[3][t]));
        cbm[((size_t)b * 48 + R) * NN + C * 128 + t] = (u16)(fkey(v) >> 16);
    }
}

// ---- scan (merged row/col via blockIdx.y): transposed bm reads,
//      block-aggregated candidate append ----
__global__ __launch_bounds__(256) void scan_kernel(
    const u16* __restrict__ rbm, const u16* __restrict__ cbm,
    int* __restrict__ cntR, int* __restrict__ cntC,
    int* __restrict__ listR, int* __restrict__ listC)
{
    const u16* bm = blockIdx.y ? cbm : rbm;
    int* cnt  = blockIdx.y ? cntC : cntR;
    int* list = blockIdx.y ? listC : listR;

    __shared__ int lcnt[48];
    __shared__ int lbase[48];
    const int t = threadIdx.x;
    if (t < 48) lcnt[t] = 0;
    const int idx = blockIdx.x * 256 + t;
    const int b = (blockIdx.x * 256) / NN;
    const int n = idx - b * NN;

    u16 ks[48];
    #pragma unroll
    for (int c = 0; c < 48; ++c)
        ks[c] = bm[((size_t)b * 48 + c) * NN + n];

    u16 mx = 0;
    #pragma unroll
    for (int c = 0; c < 48; ++c) mx = ks[c] > mx ? ks[c] : mx;
    // margin: worst-case bf16 sim error |S~-S| <= 2^-8 * sum|a_k b_k| <= 0.0039
    // (round-to-nearest f2bf, unit vectors); listing the true block needs
    // margin >= 2*0.0039 = 0.0078; 0.010 gives 28% cushion.
    float thr = inv16(mx) - 0.010f;
    u32 m0 = 0, m1 = 0;
    #pragma unroll
    for (int c = 0; c < 48; ++c) {
        if (inv16((u32)ks[c] + 1) >= thr) {
            if (c < 32) m0 |= 1u << c; else m1 |= 1u << (c - 32);
        }
    }
    __syncthreads();
    {
        u32 a = m0;
        while (a) { int c = __builtin_ctz(a); a &= a - 1; atomicAdd(&lcnt[c], 1); }
        a = m1;
        while (a) { int c = 32 + __builtin_ctz(a); a &= a - 1; atomicAdd(&lcnt[c], 1); }
    }
    __syncthreads();
    if (t < 48) { lbase[t] = atomicAdd(&cnt[b * 48 + t], lcnt[t]); lcnt[t] = 0; }
    __syncthreads();
    {
        u32 a = m0;
        while (a) {
            int c = __builtin_ctz(a); a &= a - 1;
            int pos = lbase[c] + atomicAdd(&lcnt[c], 1);
            if (pos < CAP) list[(b * 48 + c) * CAP + pos] = n;
        }
        a = m1;
        while (a) {
            int c = 32 + __builtin_ctz(a); a &= a - 1;
            int pos = lbase[c] + atomicAdd(&lcnt[c], 1);
            if (pos < CAP) list[(b * 48 + c) * CAP + pos] = n;
        }
    }
}

// ---- exact fp32 refine v4: LDS targets (conflict-free layout) +
//      LDS queries, 4q x 8t register blocking, 64-query iters ----
__global__ __launch_bounds__(256, 2) void refine_kernel(
    const float* __restrict__ f1, const float* __restrict__ f2,
    const int* __restrict__ cntR, const int* __restrict__ cntC,
    const int* __restrict__ listR, const int* __restrict__ listC,
    ull* __restrict__ rowfin, ull* __restrict__ colfin)
{
    const float* qfeat = blockIdx.z ? f2 : f1;
    const float* tfeat = blockIdx.z ? f1 : f2;
    const int* cnt  = blockIdx.z ? cntC : cntR;
    const int* list = blockIdx.z ? listC : listR;
    ull* fin = blockIdx.z ? colfin : rowfin;

    const int b = blockIdx.x / 48;
    const int C = blockIdx.x - b * 48;
    const int sub = blockIdx.y;
    int n_items = cnt[b * 48 + C];
    if (n_items > CAP) n_items = CAP;
    int chunk = (n_items + RSPLIT - 1) / RSPLIT;
    int lo = sub * chunk;
    int hi = lo + chunk; if (hi > n_items) hi = n_items;
    if (lo >= hi) return;

    __shared__ float s2f[128 * 68];   // targets (0 conflicts layout)
    __shared__ float sq[64 * 68];     // 64 staged query rows
    const int t = threadIdx.x;
    const int cg = t & 15;            // target col group (8 targets: cg+16*c8)
    const int rs = t >> 4;            // query group (4 queries: rs*4+j)
    const float* tb = tfeat + ((size_t)b * NN + C * 128) * 64;
    #pragma unroll
    for (int p = 0; p < 8; ++p) {
        int idx = p * 256 + t;
        int row = idx >> 4, c4 = idx & 15;
        *reinterpret_cast<float4*>(&s2f[row * 68 + c4 * 4]) =
            *reinterpret_cast<const float4*>(tb + row * 64 + c4 * 4);
    }
    __syncthreads();
    const int* mylist = list + (b * 48 + C) * CAP;

    for (int base = lo; base < hi; base += 64) {
        __syncthreads();   // protect sq reuse from previous iteration
        #pragma unroll
        for (int s = 0; s < 4; ++s) {
            int fi = s * 256 + t;           // 1024 float4 = 64 rows x 16
            int q = fi >> 4, c4 = fi & 15;
            int lq = base + q;
            int nn = (lq < hi) ? mylist[lq] : mylist[lo];
            *reinterpret_cast<float4*>(&sq[q * 68 + c4 * 4]) =
                *reinterpret_cast<const float4*>(
                    qfeat + ((size_t)b * NN + nn) * 64 + c4 * 4);
        }
        __syncthreads();

        float acc[4][8];   // [query j][target c8]
        #pragma unroll
        for (int j = 0; j < 4; ++j)
            #pragma unroll
            for (int c8 = 0; c8 < 8; ++c8) acc[j][c8] = 0.0f;

        #pragma unroll 4
        for (int kq = 0; kq < 16; ++kq) {
            float4 qv[4];
            #pragma unroll
            for (int j = 0; j < 4; ++j)
                qv[j] = *reinterpret_cast<const float4*>(
                    &sq[(rs * 4 + j) * 68 + kq * 4]);
            #pragma unroll
            for (int c8 = 0; c8 < 8; ++c8) {
                float4 tv = *reinterpret_cast<const float4*>(
                    &s2f[(cg + 16 * c8) * 68 + kq * 4]);
                #pragma unroll
                for (int j = 0; j < 4; ++j) {
                    acc[j][c8] = fmaf(qv[j].x, tv.x, acc[j][c8]);
                    acc[j][c8] = fmaf(qv[j].y, tv.y, acc[j][c8]);
                    acc[j][c8] = fmaf(qv[j].z, tv.z, acc[j][c8]);
                    acc[j][c8] = fmaf(qv[j].w, tv.w, acc[j][c8]);
                }
            }
        }

        // per query: best over my 8 targets, then 4-step shfl over cg lanes
        #pragma unroll
        for (int j = 0; j < 4; ++j) {
            int lq = base + rs * 4 + j;
            bool valid = lq < hi;
            float bv = acc[j][0]; int bt = cg;
            #pragma unroll
            for (int c8 = 1; c8 < 8; ++c8)
                if (acc[j][c8] > bv) { bv = acc[j][c8]; bt = cg + 16 * c8; }
            ull pk = ((ull)fkey(bv) << 32) | (u32)(~(u32)(C * 128 + bt));
            ull qq;
            qq = __shfl_xor(pk, 1); pk = pk > qq ? pk : qq;
            qq = __shfl_xor(pk, 2); pk = pk > qq ? pk : qq;
            qq = __shfl_xor(pk, 4); pk = pk > qq ? pk : qq;
            qq = __shfl_xor(pk, 8); pk = pk > qq ? pk : qq;
            if (cg == 0 && valid) {
                int n = mylist[lq];
                atomicMax(&fin[(size_t)b * NN + n], pk);
            }
        }
    }
}

// ---- Kernel B: fp8 MFMA MLP, 96 pts/block, grid=256 (1 block/CU),
//      512 thr / 8 waves, 64ch/wave, stagger + setprio + 3-buf prefetch ----

#define MLP_STEP(BUF, KB)                                                        \
    {                                                                            \
        const int kb2 = ((KB) + woff) & (NKB - 1);                               \
        __builtin_amdgcn_s_setprio(1);                                           \
        _Pragma("unroll")                                                        \
        for (int jb = 0; jb < 6; ++jb) {                                         \
            const int pt = jb * 16 + l15;                                        \
            const int sp = (kb2 * 4 + l4) ^ (pt & 7);                            \
            long bfr = *reinterpret_cast<const long*>(act + pt * 512 + sp * 8);  \
            _Pragma("unroll")                                                    \
            for (int ia = 0; ia < 4; ++ia)                                       \
                acc[ia][jb] = __builtin_amdgcn_mfma_f32_16x16x32_fp8_fp8(        \
                    BUF[ia], bfr, acc[ia][jb], 0, 0, 0);                         \
        }                                                                        \
        __builtin_amdgcn_s_setprio(0);                                           \
        if ((KB) + 3 < NKB) {                                                    \
            const int kbp = ((KB) + 3 + woff) & (NKB - 1);                       \
            _Pragma("unroll")                                                    \
            for (int ia = 0; ia < 4; ++ia)                                       \
                BUF[ia] = *reinterpret_cast<const long*>(                        \
                    wt8 + (((size_t)(chBlk0 + ia) * NKB + kbp) * 64 + lane) * 8);\
        }                                                                        \
    }

template<int K>
__device__ __forceinline__ void mlp_layer8(
    u8* act, const u8* __restrict__ wt8,
    const float* __restrict__ bias, int lane, int wid)
{
    constexpr int NKB = K / 32;
    floatx4 acc[4][6];
    #pragma unroll
    for (int ia = 0; ia < 4; ++ia)
        #pragma unroll
        for (int jb = 0; jb < 6; ++jb)
            acc[ia][jb] = (floatx4)(0.0f);

    const int l15 = lane & 15, l4 = lane >> 4;
    const int chBlk0 = wid * 4;               // (wid*64)/16
    const int woff = (wid * 2) & (NKB - 1);   // per-wave kb stagger

    long a0[4], a1[4], a2[4];
    #pragma unroll
    for (int ia = 0; ia < 4; ++ia)
        a0[ia] = *reinterpret_cast<const long*>(
            wt8 + (((size_t)(chBlk0 + ia) * NKB + ((0 + woff) & (NKB - 1))) * 64 + lane) * 8);
    #pragma unroll
    for (int ia = 0; ia < 4; ++ia)
        a1[ia] = *reinterpret_cast<const long*>(
            wt8 + (((size_t)(chBlk0 + ia) * NKB + ((1 + woff) & (NKB - 1))) * 64 + lane) * 8);
    #pragma unroll
    for (int ia = 0; ia < 4; ++ia)
        a2[ia] = *reinterpret_cast<const long*>(
            wt8 + (((size_t)(chBlk0 + ia) * NKB + ((2 + woff) & (NKB - 1))) * 64 + lane) * 8);

    #pragma unroll
    for (int kb = 0; kb < NKB; ++kb) {
        if ((kb % 3) == 0)      MLP_STEP(a0, kb)
        else if ((kb % 3) == 1) MLP_STEP(a1, kb)
        else                    MLP_STEP(a2, kb)
    }
    __syncthreads();   // all reads done before in-place overwrite

    const int ch0 = wid * 64;
    #pragma unroll
    for (int ia = 0; ia < 4; ++ia) {
        int cb = ia * 16 + l4 * 4;
        float4 bv = *reinterpret_cast<const float4*>(bias + ch0 + cb);
        #pragma unroll
        for (int jb = 0; jb < 6; ++jb) {
            int pt = jb * 16 + l15;
            u32 pk0 = f2fp8x2(fmaxf(acc[ia][jb][0] + bv.x, 0.0f),
                              fmaxf(acc[ia][jb][1] + bv.y, 0.0f));
            u32 pk1 = f2fp8x2(fmaxf(acc[ia][jb][2] + bv.z, 0.0f),
                              fmaxf(acc[ia][jb][3] + bv.w, 0.0f));
            u32 word = pk0 | (pk1 << 16);
            int s = (ch0 + cb) >> 3;
            int sp = s ^ (pt & 7);
            *reinterpret_cast<u32*>(act + pt * 512 + sp * 8 + (cb & 4)) = word;
        }
    }
    __syncthreads();
}

__global__ __launch_bounds__(512, 2) void mlp_mfma_kernel(
    const float* __restrict__ f1, const float* __restrict__ f2,
    const float* __restrict__ kps1, const float* __restrict__ kps2,
    const float* __restrict__ scales1,
    const float* __restrict__ b1, const float* __restrict__ b2,
    const float* __restrict__ b3, const float* __restrict__ b4,
    const float* __restrict__ b5,
    const u8* __restrict__ wt8,
    const ull* __restrict__ rowfin, const ull* __restrict__ colfin,
    float* __restrict__ out)
{
    __shared__ __align__(16) unsigned char lds_raw[49152];   // 96 pts x 512 ch fp8
    u8* act = lds_raw;
    float* logf = reinterpret_cast<float*>(lds_raw);

    const int t = threadIdx.x;
    const int lane = t & 63, wid = t >> 6;
    const int base = blockIdx.x * 96;
    const int b = base / NN;
    const int n0 = base % NN;

    // stage concat(f1[n], f2[match12[n]]) as fp8, swizzled; 384 active threads
    if (t < 384) {
        const int pt = t >> 2, seg = t & 3;   // 4 segs * 32 dims
        const int n = n0 + pt;
        ull rm = rowfin[(size_t)b * NN + n];
        const int m = (int)(~(u32)(rm & 0xffffffffULL));
        const float* src = (seg < 2)
            ? (f1 + ((size_t)b * NN + n) * DD + seg * 32)
            : (f2 + ((size_t)b * NN + m) * DD + (seg - 2) * 32);
        #pragma unroll
        for (int q8 = 0; q8 < 4; ++q8) {
            float4 v0 = *reinterpret_cast<const float4*>(src + q8 * 8);
            float4 v1 = *reinterpret_cast<const float4*>(src + q8 * 8 + 4);
            ull w64 = (ull)f2fp8x2(v0.x, v0.y)
                    | ((ull)f2fp8x2(v0.z, v0.w) << 16)
                    | ((ull)f2fp8x2(v1.x, v1.y) << 32)
                    | ((ull)f2fp8x2(v1.z, v1.w) << 48);
            int s = seg * 4 + q8;
            int sp = s ^ (pt & 7);
            *reinterpret_cast<ull*>(act + pt * 512 + sp * 8) = w64;
        }
    }
    __syncthreads();

    mlp_layer8<128>(act, wt8 + WT1_OFF, b1, lane, wid);
    mlp_layer8<512>(act, wt8 + WT2_OFF, b2, lane, wid);
    mlp_layer8<512>(act, wt8 + WT3_OFF, b3, lane, wid);
    mlp_layer8<512>(act, wt8 + WT4_OFF, b4, lane, wid);

    // layer 5: 512 -> 64, no relu; waves 0-3 handle 16 out-ch each (staggered)
    {
        const int l15 = lane & 15, l4 = lane >> 4;
        floatx4 acc5[6];
        #pragma unroll
        for (int jb = 0; jb < 6; ++jb) acc5[jb] = (floatx4)(0.0f);
        if (wid < 4) {
            const int woff5 = (wid * 4) & 15;
            long a_cur = *reinterpret_cast<const long*>(
                wt8 + WT5_OFF + (((size_t)wid * 16 + woff5) * 64 + lane) * 8);
            long a_nxt;
            #pragma unroll
            for (int kb = 0; kb < 16; ++kb) {
                const int kb2 = (kb + woff5) & 15;
                if (kb + 1 < 16) {
                    const int kbn = (kb + 1 + woff5) & 15;
                    a_nxt = *reinterpret_cast<const long*>(
                        wt8 + WT5_OFF + (((size_t)wid * 16 + kbn) * 64 + lane) * 8);
                }
                __builtin_amdgcn_s_setprio(1);
                #pragma unroll
                for (int jb = 0; jb < 6; ++jb) {
                    const int pt = jb * 16 + l15;
                    const int sp = (kb2 * 4 + l4) ^ (pt & 7);
                    long bfr = *reinterpret_cast<const long*>(act + pt * 512 + sp * 8);
                    acc5[jb] = __builtin_amdgcn_mfma_f32_16x16x32_fp8_fp8(
                        a_cur, bfr, acc5[jb], 0, 0, 0);
                }
                __builtin_amdgcn_s_setprio(0);
                if (kb + 1 < 16) a_cur = a_nxt;
            }
        }
        __syncthreads();   // all act reads done; lds_raw becomes logits f32
        if (wid < 4) {
            int cb = wid * 16 + l4 * 4;
            float4 bv = *reinterpret_cast<const float4*>(b5 + cb);
            #pragma unroll
            for (int jb = 0; jb < 6; ++jb) {
                int pt = jb * 16 + l15;
                float4 o;
                o.x = acc5[jb][0] + bv.x;
                o.y = acc5[jb][1] + bv.y;
                o.z = acc5[jb][2] + bv.z;
                o.w = acc5[jb][3] + bv.w;
                *reinterpret_cast<float4*>(&logf[pt * 68 + cb]) = o;
            }
        }
        __syncthreads();
    }

    if (t < 96) {
        const int pt = t;
        const int n = n0 + pt;
        const float* lrow = &logf[pt * 68];
        float mx = -1e30f;
        #pragma unroll 8
        for (int j = 0; j < OUTD; ++j) mx = fmaxf(mx, 3.0f * lrow[j]);
        float s = 0.0f, cx = 0.0f, cy = 0.0f;
        #pragma unroll 8
        for (int j = 0; j < OUTD; ++j) {
            float e = __expf(3.0f * lrow[j] - mx);
            s  += e;
            cx += e * (float)((j & 7) - 4);
            cy += e * (float)((j >> 3) - 4);
        }
        float conf = 1.0f / s;
        cx /= s; cy /= s;
        ull rm = rowfin[(size_t)b * NN + n];
        int m = (int)(~(u32)(rm & 0xffffffffULL));
        ull cm = colfin[(size_t)b * NN + m];
        int back = (int)(~(u32)(cm & 0xffffffffULL));
        bool mutual = (back == n);
        float sc = scales1[(size_t)b * NN + n];
        float x0 = kps1[((size_t)b * NN + n) * 2 + 0] + cx * sc;
        float y0 = kps1[((size_t)b * NN + n) * 2 + 1] + cy * sc;
        float x1 = kps2[((size_t)b * NN + m) * 2 + 0];
        float y1 = kps2[((size_t)b * NN + m) * 2 + 1];
        float* mt = out + ((size_t)b * NN + n) * 4;
        mt[0] = x0; mt[1] = y0; mt[2] = x1; mt[3] = y1;
        out[(size_t)BB * NN * 4 + (size_t)b * NN + n] =
            (mutual && conf > 0.25f) ? 1.0f : 0.0f;
    }
}

extern "C" void kernel_launch(void* const* d_in, const int* in_sizes, int n_in,
                              void* d_out, int out_size, void* d_ws, size_t ws_size,
                              hipStream_t stream)
{
    const float* f1  = (const float*)d_in[0];
    const float* f2  = (const float*)d_in[1];
    const float* kp1 = (const float*)d_in[2];
    const float* kp2 = (const float*)d_in[3];
    const float* sc1 = (const float*)d_in[4];
    const float* w1  = (const float*)d_in[5];
    const float* b1  = (const float*)d_in[6];
    const float* w2  = (const float*)d_in[7];
    const float* b2  = (const float*)d_in[8];
    const float* w3  = (const float*)d_in[9];
    const float* b3  = (const float*)d_in[10];
    const float* w4  = (const float*)d_in[11];
    const float* b4  = (const float*)d_in[12];
    const float* w5  = (const float*)d_in[13];
    const float* b5  = (const float*)d_in[14];

    char* ws = (char*)d_ws;
    ull* rowfin = (ull*)(ws + OFF_ROWFIN);
    ull* colfin = (ull*)(ws + OFF_COLFIN);
    u8*  wt8    = (u8*)(ws + OFF_WT);
    u16* f1t    = (u16*)(ws + OFF_F1T);
    u16* f2t    = (u16*)(ws + OFF_F2T);
    u16* rbm    = (u16*)(ws + OFF_RBM);
    u16* cbm    = (u16*)(ws + OFF_CBM);
    int* cntR   = (int*)(ws + OFF_CNTR);
    int* cntC   = (int*)(ws + OFF_CNTC);
    int* listR  = (int*)(ws + OFF_LISTR);
    int* listC  = (int*)(ws + OFF_LISTC);
    float* out  = (float*)d_out;

    prep_kernel<<<(2 * BB * NN * DD) / 256, 256, 0, stream>>>(
        w1, w2, w3, w4, w5, f1, f2, wt8, f1t, f2t, rowfin, cntR);

    dim3 gS(48, 48, BB);
    simb_kernel<<<gS, 256, 0, stream>>>(f1t, f2t, rbm, cbm);

    dim3 gScan((BB * NN) / 256, 2);
    scan_kernel<<<gScan, 256, 0, stream>>>(rbm, cbm, cntR, cntC, listR, listC);

    dim3 gR(BB * 48, RSPLIT, 2);
    refine_kernel<<<gR, 256, 0, stream>>>(f1, f2, cntR, cntC, listR, listC,
                                          rowfin, colfin);

    mlp_mfma_kernel<<<(BB * NN) / 96, 512, 0, stream>>>(
        f1, f2, kp1, kp2, sc1, b1, b2, b3, b4, b5, wt8, rowfin, colfin, out);
}